// Round 1
// baseline (2604.303 us; speedup 1.0000x reference)
//
#include <hip/hip_runtime.h>
#include <math.h>

#define NPIX 1600   // 40*40

__constant__ float c_aw[5] = {1.19f, 2.79f, 4.53f, 8.06f, 10.32f};
__constant__ float c_ah[5] = {1.98f, 4.59f, 8.92f, 5.29f, 10.65f};

// ---------------------------------------------------------------------------
// conv3x3 (SAME, stride 1) over 40x40, CIN -> 64*gridDim.z out channels.
// Block tile: 64 px (8x8 spatial) x 64 oc. Thread tile: 4 px x 4 oc.
// K staged in chunks of 8 input channels.
// ---------------------------------------------------------------------------
template<int CIN>
__global__ __launch_bounds__(256)
void conv3x3_kernel(const float* __restrict__ in, const float* __restrict__ w,
                    const float* __restrict__ scale, const float* __restrict__ shift,
                    float* __restrict__ out)
{
    const int ox  = blockIdx.x, oy = blockIdx.y;
    const int ocb = blockIdx.z << 6;
    const int tid = threadIdx.x;
    const int tx  = tid & 15;         // oc group: oc = ocb + tx*4 + k
    const int ty  = tid >> 4;         // px group: row r = ty>>1, xoff = (ty&1)*4
    const int r    = ty >> 1;
    const int xoff = (ty & 1) << 2;

    __shared__ float wl[8*9*64];      // [ic][tap][oc]
    __shared__ float patch[8*10*12];  // [ic][py][px] (stride 12)

    float acc[4][4];
#pragma unroll
    for (int j = 0; j < 4; ++j)
#pragma unroll
        for (int k = 0; k < 4; ++k) acc[j][k] = 0.f;

    const int y0 = oy*8 - 1;
    const int x0 = ox*8 - 1;

    for (int c0 = 0; c0 < CIN; c0 += 8) {
        __syncthreads();
        if (tid < 128) {
            // weights: 64 oc x 8 ic x 9 taps = 4608 floats. 2 threads per oc,
            // each reads 36 contiguous floats (9x float4, 16B aligned).
            const int o  = tid >> 1;
            const int rh = (tid & 1) * 36;
            const float* wp = w + (size_t)(ocb + o)*(CIN*9) + c0*9 + rh;
#pragma unroll
            for (int m = 0; m < 9; ++m) {
                const float4 v = ((const float4*)wp)[m];
                const int rr = rh + m*4;   // rr = ic*9 + tap
                wl[(rr+0)*64 + o] = v.x;
                wl[(rr+1)*64 + o] = v.y;
                wl[(rr+2)*64 + o] = v.z;
                wl[(rr+3)*64 + o] = v.w;
            }
        } else {
            // input patch 8ch x 10x10 (zero-padded borders)
            const int t = tid - 128;
            for (int e = t; e < 800; e += 128) {
                const int ch  = e / 100;
                const int rem = e - ch*100;
                const int py  = rem / 10;
                const int pxx = rem - py*10;
                const int gy = y0 + py, gx = x0 + pxx;
                float v = 0.f;
                if ((unsigned)gy < 40u && (unsigned)gx < 40u)
                    v = in[(size_t)(c0+ch)*NPIX + gy*40 + gx];
                patch[ch*120 + py*12 + pxx] = v;
            }
        }
        __syncthreads();
#pragma unroll
        for (int i = 0; i < 8; ++i) {
#pragma unroll
            for (int dy = 0; dy < 3; ++dy) {
                const float* prow = &patch[i*120 + (r+dy)*12 + xoff];
                float a[6];
#pragma unroll
                for (int q = 0; q < 6; ++q) a[q] = prow[q];
#pragma unroll
                for (int dx = 0; dx < 3; ++dx) {
                    const float4 b = *(const float4*)&wl[(i*9 + dy*3 + dx)*64 + (tx<<2)];
#pragma unroll
                    for (int j = 0; j < 4; ++j) {
                        const float av = a[dx + j];
                        acc[j][0] = fmaf(av, b.x, acc[j][0]);
                        acc[j][1] = fmaf(av, b.y, acc[j][1]);
                        acc[j][2] = fmaf(av, b.z, acc[j][2]);
                        acc[j][3] = fmaf(av, b.w, acc[j][3]);
                    }
                }
            }
        }
    }

    // epilogue: BN + leaky ReLU, coalesced float4 stores
    const int gy = oy*8 + r;
    const int gx = ox*8 + xoff;
#pragma unroll
    for (int k = 0; k < 4; ++k) {
        const int oc = ocb + (tx<<2) + k;
        const float s = scale[oc], sh = shift[oc];
        float4 o4; float v;
        v = fmaf(acc[0][k], s, sh); o4.x = v > 0.f ? v : 0.1f*v;
        v = fmaf(acc[1][k], s, sh); o4.y = v > 0.f ? v : 0.1f*v;
        v = fmaf(acc[2][k], s, sh); o4.z = v > 0.f ? v : 0.1f*v;
        v = fmaf(acc[3][k], s, sh); o4.w = v > 0.f ? v : 0.1f*v;
        *(float4*)&out[(size_t)oc*NPIX + gy*40 + gx] = o4;
    }
}

// ---------------------------------------------------------------------------
// conv1x1 512->64 @80x80 + BN + lrelu + reorg(s=2), writes X channels 0..255
// ---------------------------------------------------------------------------
__global__ __launch_bounds__(256)
void conv1x1_reorg_kernel(const float* __restrict__ in, const float* __restrict__ w,
                          const float* __restrict__ scale, const float* __restrict__ shift,
                          float* __restrict__ X)
{
    const int px0 = blockIdx.x << 6;   // 100 blocks x 64 linear pixels (of 6400)
    const int tid = threadIdx.x;
    const int tx  = tid & 15;
    const int ty  = tid >> 4;

    __shared__ float il[8*64];
    __shared__ float wlr[8*64];

    float acc[4][4];
#pragma unroll
    for (int j = 0; j < 4; ++j)
#pragma unroll
        for (int k = 0; k < 4; ++k) acc[j][k] = 0.f;

    for (int c0 = 0; c0 < 512; c0 += 8) {
        __syncthreads();
        {
            int e = tid;
#pragma unroll
            for (int q = 0; q < 2; ++q, e += 256) {
                const int ch = e >> 6, p = e & 63;
                il[ch*64 + p] = in[(size_t)(c0+ch)*6400 + px0 + p];
            }
            e = tid;
#pragma unroll
            for (int q = 0; q < 2; ++q, e += 256) {
                const int o = e >> 3, cc = e & 7;
                wlr[cc*64 + o] = w[o*512 + c0 + cc];
            }
        }
        __syncthreads();
#pragma unroll
        for (int cc = 0; cc < 8; ++cc) {
            const float4 a4 = *(const float4*)&il[cc*64 + (ty<<2)];
            const float4 b4 = *(const float4*)&wlr[cc*64 + (tx<<2)];
            const float a[4] = {a4.x, a4.y, a4.z, a4.w};
            const float b[4] = {b4.x, b4.y, b4.z, b4.w};
#pragma unroll
            for (int j = 0; j < 4; ++j)
#pragma unroll
                for (int k = 0; k < 4; ++k)
                    acc[j][k] = fmaf(a[j], b[k], acc[j][k]);
        }
    }

#pragma unroll
    for (int j = 0; j < 4; ++j) {
        const int px = px0 + (ty<<2) + j;
        const int y2 = px / 80, x2 = px - y2*80;
        const int q  = (y2 & 1)*2 + (x2 & 1);
        const int yo = y2 >> 1, xo = x2 >> 1;
#pragma unroll
        for (int k = 0; k < 4; ++k) {
            const int oc = (tx<<2) + k;
            float v = fmaf(acc[j][k], scale[oc], shift[oc]);
            v = v > 0.f ? v : 0.1f*v;
            X[(size_t)(q*64 + oc)*NPIX + yo*40 + xo] = v;
        }
    }
}

// ---------------------------------------------------------------------------
// conv1x1 1024->125 @40x40 (no bias here; readers add bp)
// ---------------------------------------------------------------------------
__global__ __launch_bounds__(256)
void conv1x1_pred_kernel(const float* __restrict__ in, const float* __restrict__ w,
                         float* __restrict__ pred)
{
    const int px0 = blockIdx.x << 5;   // 50 blocks x 32 px
    const int tid = threadIdx.x;
    const int tx  = tid & 15;
    const int ty  = tid >> 4;

    __shared__ float il[8*32];
    __shared__ float wlp[8*128];

    float acc[2][8];
#pragma unroll
    for (int j = 0; j < 2; ++j)
#pragma unroll
        for (int k = 0; k < 8; ++k) acc[j][k] = 0.f;

    for (int c0 = 0; c0 < 1024; c0 += 8) {
        __syncthreads();
        {
            const int ch = tid >> 5, p = tid & 31;
            il[ch*32 + p] = in[(size_t)(c0+ch)*NPIX + px0 + p];
        }
#pragma unroll
        for (int q = 0; q < 4; ++q) {
            const int e = tid + q*256;
            const int o = e >> 3, cc = e & 7;
            wlp[cc*128 + o] = (o < 125) ? w[o*1024 + c0 + cc] : 0.f;
        }
        __syncthreads();
#pragma unroll
        for (int cc = 0; cc < 8; ++cc) {
            const float a0 = il[cc*32 + (ty<<1)];
            const float a1 = il[cc*32 + (ty<<1) + 1];
            const float4 b0 = *(const float4*)&wlp[cc*128 + (tx<<3)];
            const float4 b1 = *(const float4*)&wlp[cc*128 + (tx<<3) + 4];
            const float b[8] = {b0.x,b0.y,b0.z,b0.w,b1.x,b1.y,b1.z,b1.w};
#pragma unroll
            for (int k = 0; k < 8; ++k) {
                acc[0][k] = fmaf(a0, b[k], acc[0][k]);
                acc[1][k] = fmaf(a1, b[k], acc[1][k]);
            }
        }
    }
#pragma unroll
    for (int k = 0; k < 8; ++k) {
        const int oc = (tx<<3) + k;
        if (oc < 125) {
#pragma unroll
            for (int j = 0; j < 2; ++j)
                pred[(size_t)oc*NPIX + px0 + (ty<<1) + j] = acc[j][k];
        }
    }
}

// ---------------------------------------------------------------------------
// scores = sigmoid(conf) * softmax(cls) for 8000 (px,anchor) pairs
// ---------------------------------------------------------------------------
__global__ __launch_bounds__(256)
void score_kernel(const float* __restrict__ pred, const float* __restrict__ bp,
                  float* __restrict__ scores)
{
    const int id = blockIdx.x*256 + threadIdx.x;
    if (id >= 8000) return;
    const int a  = id / 1600;
    const int px = id - a*1600;
    const float conf = pred[a*NPIX + px] + bp[a];
    float cls[20];
    float m = -INFINITY;
#pragma unroll
    for (int c = 0; c < 20; ++c) {
        cls[c] = pred[(5 + a*20 + c)*NPIX + px] + bp[5 + a*20 + c];
        m = fmaxf(m, cls[c]);
    }
    float ssum = 0.f;
#pragma unroll
    for (int c = 0; c < 20; ++c) { cls[c] = expf(cls[c] - m); ssum += cls[c]; }
    const float sig = 1.f / (1.f + expf(-conf));
    const float f = sig / ssum;
    const int base = (px*5 + a)*20;
#pragma unroll
    for (int c = 0; c < 20; ++c) scores[base + c] = cls[c] * f;
}

// ---------------------------------------------------------------------------
// exact top-100 via 3-level radix select on positive-float bits (12/12/8)
// ---------------------------------------------------------------------------
__global__ __launch_bounds__(256)
void hist1_kernel(const float* __restrict__ scores, unsigned* __restrict__ hist)
{
    __shared__ unsigned h[4096];
    for (int i = threadIdx.x; i < 4096; i += 256) h[i] = 0u;
    __syncthreads();
    for (int id = blockIdx.x*256 + threadIdx.x; id < 160000; id += 80*256)
        atomicAdd(&h[__float_as_uint(scores[id]) >> 20], 1u);
    __syncthreads();
    for (int i = threadIdx.x; i < 4096; i += 256)
        if (h[i]) atomicAdd(&hist[i], h[i]);
}

__global__ __launch_bounds__(256)
void hist2_kernel(const float* __restrict__ scores, const unsigned* __restrict__ meta,
                  unsigned* __restrict__ hist)
{
    const int id = blockIdx.x*256 + threadIdx.x;
    if (id >= 160000) return;
    const unsigned u = __float_as_uint(scores[id]);
    if ((u >> 20) == meta[0]) atomicAdd(&hist[(u >> 8) & 0xFFFu], 1u);
}

__global__ __launch_bounds__(256)
void hist3_kernel(const float* __restrict__ scores, const unsigned* __restrict__ meta,
                  unsigned* __restrict__ hist)
{
    const int id = blockIdx.x*256 + threadIdx.x;
    if (id >= 160000) return;
    const unsigned u = __float_as_uint(scores[id]);
    const unsigned key = (meta[0] << 12) | meta[2];
    if ((u >> 8) == key) atomicAdd(&hist[u & 0xFFu], 1u);
}

__global__ __launch_bounds__(256)
void scan_kernel(const unsigned* __restrict__ hist, int nbins,
                 unsigned* __restrict__ meta, int mode)
{
    __shared__ unsigned seg[256];
    const int tid = threadIdx.x;
    const int spb = nbins >> 8;    // bins per segment (16 or 1)
    unsigned s = 0;
    for (int k = 0; k < spb; ++k) s += hist[tid*spb + k];
    seg[tid] = s;
    __syncthreads();
    if (tid == 0) {
        unsigned need = 100u;
        if (mode == 2) need = 100u - meta[1];
        else if (mode == 3) need = 100u - meta[3];
        unsigned cum = 0;
        int sgi = 255;
        while (sgi > 0 && cum + seg[sgi] < need) { cum += seg[sgi]; --sgi; }
        int b = sgi*spb + spb - 1;
        while (b > sgi*spb && cum + hist[b] < need) { cum += hist[b]; --b; }
        if (mode == 1)      { meta[0] = (unsigned)b; meta[1] = cum; }
        else if (mode == 2) { meta[2] = (unsigned)b; meta[3] = meta[1] + cum; }
        else {
            meta[4] = (meta[0] << 20) | (meta[2] << 8) | (unsigned)b;  // exact bits of 100th value
            meta[5] = meta[3] + cum;                                    // n strictly greater
        }
    }
}

__global__ __launch_bounds__(256)
void collect_kernel(const float* __restrict__ scores, unsigned* __restrict__ meta,
                    float* __restrict__ gt_val, unsigned* __restrict__ gt_idx,
                    unsigned* __restrict__ eq_idx)
{
    const int id = blockIdx.x*256 + threadIdx.x;
    if (id >= 160000) return;
    const float v = scores[id];
    const unsigned u = __float_as_uint(v);
    const unsigned T = meta[4];
    if (u > T) {
        const unsigned p = atomicAdd(&meta[8], 1u);
        if (p < 128u) { gt_val[p] = v; gt_idx[p] = (unsigned)id; }
    } else if (u == T) {
        const unsigned p = atomicAdd(&meta[9], 1u);
        if (p < 1024u) eq_idx[p] = (unsigned)id;
    }
}

// ---------------------------------------------------------------------------
// final: assemble top-100 (stable ties), bitonic sort desc, decode, NMS, write
// ---------------------------------------------------------------------------
__global__ __launch_bounds__(128)
void final_kernel(const float* __restrict__ pred, const float* __restrict__ bp,
                  const unsigned* __restrict__ meta,
                  const float* __restrict__ gt_val, const unsigned* __restrict__ gt_idx,
                  const unsigned* __restrict__ eq_idx,
                  float* __restrict__ out)
{
    __shared__ float    sval[128];
    __shared__ unsigned sidx[128];
    __shared__ float bx1[100], by1[100], bx2[100], by2[100], sarea[100], sscore[100];
    __shared__ int   slab[100];
    __shared__ int   skeep[100];

    const int tid = threadIdx.x;
    const unsigned T    = meta[4];
    const unsigned n_gt = meta[5];
    const unsigned n_eq = meta[9] < 1024u ? meta[9] : 1024u;
    const int n_take = 100 - (int)n_gt;

    sval[tid] = -1.f;
    sidx[tid] = 0xFFFFFFFFu;
    if (tid < (int)n_gt) { sval[tid] = gt_val[tid]; sidx[tid] = gt_idx[tid]; }
    __syncthreads();
    if (tid == 0) {
        // values equal to threshold: stable top_k takes smallest indices first
        unsigned lastp1 = 0;
        const float tv = __uint_as_float(T);
        for (int t = 0; t < n_take; ++t) {
            unsigned best = 0xFFFFFFFFu;
            for (unsigned e = 0; e < n_eq; ++e) {
                const unsigned v = eq_idx[e];
                if (v >= lastp1 && v < best) best = v;
            }
            sval[n_gt + t] = tv;
            sidx[n_gt + t] = best;
            lastp1 = best + 1;
        }
    }
    __syncthreads();

    // bitonic sort of 128 (desc value, ties asc index); padding (-1) sinks
    for (int k = 2; k <= 128; k <<= 1) {
        for (int j = k >> 1; j > 0; j >>= 1) {
            const int ixj = tid ^ j;
            if (ixj > tid) {
                const float v0 = sval[tid], v1 = sval[ixj];
                const unsigned i0 = sidx[tid], i1 = sidx[ixj];
                const bool prec = (v0 > v1) || (v0 == v1 && i0 < i1);
                const bool asc  = ((tid & k) == 0);
                if (asc ? !prec : prec) {
                    sval[tid] = v1; sval[ixj] = v0;
                    sidx[tid] = i1; sidx[ixj] = i0;
                }
            }
            __syncthreads();
        }
    }

    if (tid < 100) {
        const float sc = sval[tid];
        const unsigned idx = sidx[tid];
        const int ai   = (int)(idx / 20u);
        const int lab  = (int)(idx - (unsigned)ai*20u);
        const int cell = ai / 5;
        const int a    = ai - cell*5;
        const int gx = cell % 40, gy = cell / 40;
        const int rb = 105 + a*4;
        const float t0 = pred[(rb+0)*NPIX + cell] + bp[rb+0];
        const float t1 = pred[(rb+1)*NPIX + cell] + bp[rb+1];
        const float t2 = pred[(rb+2)*NPIX + cell] + bp[rb+2];
        const float t3 = pred[(rb+3)*NPIX + cell] + bp[rb+3];
        const float cx = (1.f/(1.f+expf(-t0)) + (float)gx) * 32.f;
        const float cy = (1.f/(1.f+expf(-t1)) + (float)gy) * 32.f;
        const float bw = expf(t2) * c_aw[a] * 32.f;
        const float bh = expf(t3) * c_ah[a] * 32.f;
        bx1[tid] = cx - 0.5f*bw;
        by1[tid] = cy - 0.5f*bh;
        bx2[tid] = cx + 0.5f*bw;
        by2[tid] = cy + 0.5f*bh;
        sarea[tid]  = (bx2[tid]-bx1[tid]) * (by2[tid]-by1[tid]);
        slab[tid]   = lab;
        sscore[tid] = sc;
        skeep[tid]  = (sc > 0.001f) ? 1 : 0;
    }
    __syncthreads();

    // greedy class-aware NMS (reference semantics)
    for (int i = 0; i < 99; ++i) {
        if (tid < 100 && tid > i) {
            if (skeep[i] && skeep[tid] && slab[tid] == slab[i]) {
                const float xx1 = fmaxf(bx1[i], bx1[tid]);
                const float yy1 = fmaxf(by1[i], by1[tid]);
                const float xx2 = fminf(bx2[i], bx2[tid]);
                const float yy2 = fminf(by2[i], by2[tid]);
                const float inter = fmaxf(1e-10f, xx2-xx1) * fmaxf(1e-10f, yy2-yy1);
                const float iou = inter / (sarea[i] + sarea[tid] - inter);
                if (iou > 0.6f) skeep[tid] = 0;
            }
        }
        __syncthreads();
    }

    if (tid < 100) {
        const bool kp = skeep[tid] != 0;
        const float q[4] = {bx1[tid], by1[tid], bx2[tid], by2[tid]};
#pragma unroll
        for (int k = 0; k < 4; ++k) {
            float v = q[k] / 1280.f;
            v = fminf(fmaxf(v, 0.f), 1.f);
            out[tid*4 + k] = kp ? v : 0.f;
        }
        out[400 + tid] = kp ? sscore[tid] : 0.f;
        out[500 + tid] = kp ? (float)slab[tid] : -1.f;
        out[600 + tid] = kp ? 1.f : 0.f;
    }
}

// ---------------------------------------------------------------------------
extern "C" void kernel_launch(void* const* d_in, const int* in_sizes, int n_in,
                              void* d_out, int out_size, void* d_ws, size_t ws_size,
                              hipStream_t stream)
{
    const float* c4  = (const float*)d_in[0];
    const float* c5  = (const float*)d_in[1];
    const float* w1a = (const float*)d_in[2];
    const float* s1a = (const float*)d_in[3];
    const float* b1a = (const float*)d_in[4];
    const float* w1b = (const float*)d_in[5];
    const float* s1b = (const float*)d_in[6];
    const float* b1b = (const float*)d_in[7];
    const float* wr  = (const float*)d_in[8];
    const float* sr  = (const float*)d_in[9];
    const float* br  = (const float*)d_in[10];
    const float* w2  = (const float*)d_in[11];
    const float* s2  = (const float*)d_in[12];
    const float* b2  = (const float*)d_in[13];
    const float* wp  = (const float*)d_in[14];
    const float* bp  = (const float*)d_in[15];

    float* ws   = (float*)d_ws;
    float* p5a  = ws;                         // 1024*1600
    float* X    = p5a + 1024*NPIX;            // 1280*1600 (concat buffer)
    float* p5c  = X + 1280*NPIX;              // 1024*1600
    float* pred = p5c + 1024*NPIX;            // 125*1600
    float* scores = pred + 125*NPIX;          // 160000
    unsigned* hist1 = (unsigned*)(scores + 160000);  // 4096
    unsigned* hist2 = hist1 + 4096;                  // 4096
    unsigned* hist3 = hist2 + 4096;                  // 256
    unsigned* meta  = hist3 + 256;                   // 16
    float*    gt_val = (float*)(meta + 16);          // 128
    unsigned* gt_idx = (unsigned*)(gt_val + 128);    // 128
    unsigned* eq_idx = gt_idx + 128;                 // 1024

    hipMemsetAsync(hist1, 0, (4096 + 4096 + 256 + 16) * sizeof(unsigned), stream);

    const dim3 g3(5, 5, 16);
    conv3x3_kernel<1024><<<g3, 256, 0, stream>>>(c5,  w1a, s1a, b1a, p5a);
    conv3x3_kernel<1024><<<g3, 256, 0, stream>>>(p5a, w1b, s1b, b1b, X + 256*NPIX);
    conv1x1_reorg_kernel<<<100, 256, 0, stream>>>(c4, wr, sr, br, X);
    conv3x3_kernel<1280><<<g3, 256, 0, stream>>>(X, w2, s2, b2, p5c);
    conv1x1_pred_kernel<<<50, 256, 0, stream>>>(p5c, wp, pred);

    score_kernel<<<32, 256, 0, stream>>>(pred, bp, scores);
    hist1_kernel<<<80, 256, 0, stream>>>(scores, hist1);
    scan_kernel<<<1, 256, 0, stream>>>(hist1, 4096, meta, 1);
    hist2_kernel<<<625, 256, 0, stream>>>(scores, meta, hist2);
    scan_kernel<<<1, 256, 0, stream>>>(hist2, 4096, meta, 2);
    hist3_kernel<<<625, 256, 0, stream>>>(scores, meta, hist3);
    scan_kernel<<<1, 256, 0, stream>>>(hist3, 256, meta, 3);
    collect_kernel<<<625, 256, 0, stream>>>(scores, meta, gt_val, gt_idx, eq_idx);
    final_kernel<<<1, 128, 0, stream>>>(pred, bp, meta, gt_val, gt_idx, eq_idx, (float*)d_out);
}